// Round 8
// baseline (1772.301 us; speedup 1.0000x reference)
//
#include <hip/hip_runtime.h>
#include <math.h>

// Problem constants (fixed by setup_inputs)
#define T_DIM 1000
#define BB    16
#define XD    8
#define YD    4
#define HD    48
#define NITER 200     // iterations (device scalar d_in[26], fixed)
#define GAMMA 1e-4f

// fused-scan geometry
#define HALO  25      // ghost columns each side
#define FUSE  25      // iterations fused per launch (valid shrink = HALO)
#define NLNCH 8       // FUSE*NLNCH == NITER
#define SC    128     // staged columns per block (8 waves x 16)
#define EFF   (SC - 2*HALO)   // 78 effective columns
#define NTI   13      // ceil(1000/EFF)
#define HP    56      // padded h-width (shorts) for [col][h] LDS tiles

typedef __attribute__((ext_vector_type(8))) short bf16x8;
typedef __attribute__((ext_vector_type(4))) float f32x4;
typedef __attribute__((ext_vector_type(4))) unsigned short us4;
typedef __attribute__((ext_vector_type(2))) unsigned u32x2;
typedef __attribute__((ext_vector_type(4))) unsigned u32x4;

#define MFMA16(a,b,c) __builtin_amdgcn_mfma_f32_16x16x32_bf16((a),(b),(c),0,0,0)

__device__ inline unsigned short f2b(float x) {
  union { float f; unsigned u; } v; v.f = x;
  unsigned r = (v.u + 0x7FFFu + ((v.u >> 16) & 1u)) >> 16;
  return (unsigned short)r;
}
__device__ inline float b2fl(unsigned p) {  // low bf16 of a packed pair -> f32
  union { unsigned u; float f; } v; v.u = p << 16; return v.f;
}
__device__ inline float b2fh(unsigned p) {  // high bf16 of a packed pair -> f32
  union { unsigned u; float f; } v; v.u = p & 0xFFFF0000u; return v.f;
}
__device__ inline bf16x8 ldg8(const unsigned short* p) { return *(const bf16x8*)p; }
__device__ inline unsigned pk2(float a, float b) {
  return (unsigned)f2b(a) | ((unsigned)f2b(b) << 16);
}
__device__ inline bf16x8 mk8(unsigned a, unsigned b, unsigned c, unsigned d) {
  union { u32x4 u; bf16x8 v; } t; t.u[0]=a; t.u[1]=b; t.u[2]=c; t.u[3]=d; return t.v;
}
// 4-lane quad exchange (l16 preserved), VALIDATED mapping (R4-R7 passed):
// qswap(x0,x1) at quad q: A = x_{q>>1}@quad 2(q&1), B = x_{q>>1}@quad 2(q&1)+1.
__device__ inline void qswap(unsigned x0, unsigned x1, unsigned &A, unsigned &B) {
  u32x2 s = __builtin_amdgcn_permlane32_swap(x0, x1, false, false);
  u32x2 t = __builtin_amdgcn_permlane16_swap(s[0], s[1], false, false);
  A = t[0]; B = t[1];
}
// Redistribute 12 f32 rows/lane (C-layout) into MFMA B-frags c0 (k0..31) and
// c1 (k32..63; k48=bias 1.0). Bit-identical to an LDS round-trip.
__device__ inline void frag48(const f32x4 m0, const f32x4 m1, const f32x4 m2,
                              int quad, bf16x8 &c0, bf16x8 &c1) {
  unsigned p00 = pk2(m0[0], m0[1]), p01 = pk2(m0[2], m0[3]);
  unsigned p10 = pk2(m1[0], m1[1]), p11 = pk2(m1[2], m1[3]);
  unsigned p20 = pk2(m2[0], m2[1]), p21 = pk2(m2[2], m2[3]);
  unsigned A0,B0,A1,B1,A2,B2,A3,B3;
  qswap(p00, p10, A0, B0);
  qswap(p01, p11, A1, B1);
  qswap(p20, p20, A2, B2);
  qswap(p21, p21, A3, B3);
  c0 = mk8(A0, A1, B0, B1);
  unsigned t0, t1, t2, t3;
  if (quad < 2)       { t0 = A2; t1 = A3; t2 = B2; t3 = B3; }
  else if (quad == 2) { t0 = 0x3F80u; t1 = 0; t2 = 0; t3 = 0; }
  else                { t0 = 0; t1 = 0; t2 = 0; t3 = 0; }
  c1 = mk8(t0, t1, t2, t3);
}

// ---------------- precompute: inverses + fused mats + message matrices ----------------
// mats: Qi[0..63], QiF[64..127], FtQi[128..191], FtQiF[192..255], HtRi[256..287], HtRiH[288..351]
// Mmsg[4][16][32] bf16 (0=A_hi,1=A_lo,2=B_hi,3=B_lo), 16B chunks XOR-swizzled by row&3.
__global__ __launch_bounds__(64) void precompute_mats_kernel(
    const float* __restrict__ F, const float* __restrict__ Hm,
    const float* __restrict__ Q, const float* __restrict__ R,
    float* __restrict__ mats, unsigned short* __restrict__ Mmsg)
{
  __shared__ float sQi[64], sRi[16], sF[64], sH[32], sFtQi[64], sHtRi[32];
  __shared__ float sQiF[64], sFtQiF[64], sHtRiH[64];
  const int t = threadIdx.x;
  if (t < 64) sF[t] = F[t];
  if (t < 32) sH[t] = Hm[t];
  {
    float col[8];
    #pragma unroll
    for (int i = 0; i < 8; i++)
      col[i] = (t < 8) ? Q[i*8 + t] : ((t < 16 && i == t - 8) ? 1.f : 0.f);
    #pragma unroll
    for (int c = 0; c < 8; c++) {
      float Mcc = __shfl(col[c], c);
      float f[8];
      #pragma unroll
      for (int r = 0; r < 8; r++) f[r] = __shfl(col[r], c);
      float newc = col[c] / Mcc;
      col[c] = newc;
      #pragma unroll
      for (int r = 0; r < 8; r++) if (r != c) col[r] -= f[r] * newc;
    }
    if (t >= 8 && t < 16) {
      #pragma unroll
      for (int i = 0; i < 8; i++) sQi[i*8 + (t - 8)] = col[i];
    }
  }
  {
    float col[4];
    #pragma unroll
    for (int i = 0; i < 4; i++)
      col[i] = (t < 4) ? R[i*4 + t] : ((t < 8 && i == t - 4) ? 1.f : 0.f);
    #pragma unroll
    for (int c = 0; c < 4; c++) {
      float Mcc = __shfl(col[c], c);
      float f[4];
      #pragma unroll
      for (int r = 0; r < 4; r++) f[r] = __shfl(col[r], c);
      float newc = col[c] / Mcc;
      col[c] = newc;
      #pragma unroll
      for (int r = 0; r < 4; r++) if (r != c) col[r] -= f[r] * newc;
    }
    if (t >= 4 && t < 8) {
      #pragma unroll
      for (int i = 0; i < 4; i++) sRi[i*4 + (t - 4)] = col[i];
    }
  }
  __syncthreads();
  const int i = t >> 3, j = t & 7;
  mats[t] = sQi[t];
  { float s = 0.f; for (int k = 0; k < 8; k++) s += sQi[i*8+k] * sF[k*8+j]; mats[64 + t] = s; sQiF[t] = s; }
  { float s = 0.f; for (int k = 0; k < 8; k++) s += sF[k*8+i] * sQi[k*8+j]; mats[128 + t] = s; sFtQi[t] = s; }
  if (t < 32) {
    int ii = t >> 2, z = t & 3;
    float s = 0.f; for (int y = 0; y < 4; y++) s += sH[y*8+ii] * sRi[y*4+z];
    mats[256 + t] = s; sHtRi[t] = s;
  }
  __syncthreads();
  { float s = 0.f; for (int k = 0; k < 8; k++) s += sFtQi[i*8+k] * sF[k*8+j]; mats[192 + t] = s; sFtQiF[t] = s; }
  { float s = 0.f; for (int z = 0; z < 4; z++) s += sHtRi[i*4+z] * sH[z*8+j]; mats[288 + t] = s; sHtRiH[t] = s; }
  __syncthreads();
  for (int ii = t; ii < 2048; ii += 64) {
    int m = ii >> 9;            // 0..3: A_hi, A_lo, B_hi, B_lo
    int row = (ii >> 5) & 15;
    int kk = ii & 31;
    int g = m >> 1, hilo = m & 1;
    int q = row >> 2, r = row & 3, x = 2*q + (r & 1);
    int kb = kk >> 3, jj = kk & 7;
    float c = 0.f;
    if (g == 0) {
      if (r < 2) c = (kb == 0) ? sQiF[x*8+jj] : (kb >= 2) ? -sQi[x*8+jj] : 0.f;
      else       c = (kb == 1) ? sFtQi[x*8+jj] : (kb >= 2) ? -sFtQiF[x*8+jj] : 0.f;
    } else {
      if (r < 2) c = (kb >= 2) ? -sHtRiH[x*8+jj] : 0.f;
      else       c = (kb == 0) ? sQiF[x*8+jj] : (kb == 1) ? sFtQi[x*8+jj]
                   : -(sQi[x*8+jj] + sFtQiF[x*8+jj] + sHtRiH[x*8+jj]);
    }
    unsigned short hv = f2b(c);
    unsigned short out = hv;
    if (hilo) out = f2b(c - b2fl((unsigned)hv));
    Mmsg[(m*16 + row)*32 + ((kb ^ (row & 3)) * 8) + jj] = out;
  }
}

// ---------------- precompute per (b,t): hy (bf16), xs0, mconst ----------------
__global__ void precompute_bt_kernel(const float* __restrict__ ys,
                                     const float* __restrict__ W_hy, const float* __restrict__ b_hy,
                                     const float* __restrict__ Hm, const float* __restrict__ mats,
                                     unsigned short* __restrict__ hy_b,
                                     float* __restrict__ mconst, float* __restrict__ xs0)
{
  int idx = blockIdx.x * 256 + threadIdx.x;
  if (idx >= BB * T_DIM) return;
  int b = idx / T_DIM, t = idx - b * T_DIM;
  float yy[YD];
  #pragma unroll
  for (int y = 0; y < YD; y++) yy[y] = ys[(b*T_DIM + t)*YD + y];
  #pragma unroll 4
  for (int h = 0; h < HD; h++) {
    float s = b_hy[h];
    #pragma unroll
    for (int y = 0; y < YD; y++) s += W_hy[h*YD+y] * yy[y];
    hy_b[(b*T_DIM + t)*HD + h] = f2b(s);
  }
  const float* HtRi = mats + 256;
  #pragma unroll
  for (int x = 0; x < XD; x++) {
    float s0 = 0.f, s1 = 0.f;
    #pragma unroll
    for (int y = 0; y < YD; y++) {
      s0 += Hm[y*XD + x] * yy[y];
      s1 += HtRi[x*YD + y] * yy[y];
    }
    xs0[(b*XD + x)*T_DIM + t]    = s0;
    mconst[(b*XD + x)*T_DIM + t] = s1;
  }
}

// ---------------- weight conversion to padded bf16 with bias folded into K ----------------
struct WP {
  const float *W1[3], *b1[3], *W2[3], *b2[3], *Wih, *bih, *Whh, *bhh, *Wdec, *bdec;
  unsigned short *W1b, *W2b, *Wihb, *Whhb, *Wdecb;
};
__global__ void convert_weights_kernel(WP p) {
  int idx = blockIdx.x * 256 + threadIdx.x;
  int stride = gridDim.x * 256;
  // W1b: [3][48][128] : cols 0..103 = W1, col 104 = b1, rest 0
  for (int i = idx; i < 3*48*128; i += stride) {
    int e = i / (48*128), r = (i / 128) % 48, k = i & 127;
    float v = (k < 104) ? p.W1[e][r*104 + k] : (k == 104) ? p.b1[e][r] : 0.f;
    p.W1b[i] = (k <= 104) ? f2b(v) : 0;
  }
  // W2b: [3][48][64] : cols 0..47 = W2, col 48 = b2
  for (int i = idx; i < 3*48*64; i += stride) {
    int e = i / (48*64), r = (i / 64) % 48, k = i & 63;
    float v = (k < HD) ? p.W2[e][r*HD + k] : (k == HD) ? p.b2[e][r] : 0.f;
    p.W2b[i] = (k <= HD) ? f2b(v) : 0;
  }
  // Wihb/Whhb: [144][64] : col 48 = bias
  for (int i = idx; i < 144*64; i += stride) {
    int r = i >> 6, k = i & 63;
    p.Wihb[i] = (k < HD) ? f2b(p.Wih[r*HD + k]) : (k == HD) ? f2b(p.bih[r]) : 0;
    p.Whhb[i] = (k < HD) ? f2b(p.Whh[r*HD + k]) : (k == HD) ? f2b(p.bhh[r]) : 0;
  }
  // Wdecb: [16][64]
  for (int i = idx; i < 16*64; i += stride) {
    int r = i >> 6, k = i & 63;
    unsigned short v = 0;
    if (r < XD) {
      if (k < HD) v = f2b(p.Wdec[r*HD + k]);
      else if (k == HD) v = f2b(p.bdec[r]);
    }
    p.Wdecb[i] = v;
  }
}

// ---------------- fused multi-iteration scan kernel ----------------
struct FP {
  const unsigned short* Mmsg;
  const float* mconst;
  const unsigned short* hy_b;
  const unsigned short *W1b, *W2b, *Wihb, *Whhb, *Wdecb;
  const float *xs_src, *hx_src;   // state after iteration k0-1
  float* hx_dst;                  // state after iteration k0+FUSE-1
  float* out;                     // [BXT final][NITER][B][XD][T]
  int k0;
};

__global__ __launch_bounds__(512, 2)
void fused_kernel(FP P)
{
  // R8: two rotating-value register carries shorten the DS head-of-chain:
  //  (1) ctr0/ctrg (center-hx MFMA frags) carried across iterations -- the
  //      decoder's d0/d1 = frag48(hnew) IS next iter's ctr0/ctrg (validated
  //      frag48<->LDS identity, incl. quad2 bias word and quad3 zeros-vs-
  //      garbage*0 equivalence). Removes 2 ds_reads + ~120cy gate at iter top.
  //  (2) hy frags hoisted (true per-lane invariants, 8 VGPR -- rotating/small
  //      carries survive the 128-VGPR cap; only big invariant ARRAYS spill).
  // Spin poll is plain (no s_sleep 64cy granularity).
  __shared__ __align__(16) unsigned short s_hx[2][SC+2][HP];  // bf16 hx, dbuf, rows=col+1, col 48=1.0(bias)
  __shared__ __align__(16) unsigned short s_hy[SC][HD];       // bf16 hy (const)
  __shared__ __align__(16) float s_xs[2][SC+2][12];           // fp32 xs, dbuf
  __shared__ __align__(16) unsigned short s_Mmsg[2048];       // message matrices (4x16x32)
  // bf16 weights staged in LDS once per block; 16B chunk c of row r stored at
  // chunk c^(r&7). W2b + Wdecb stay global (L1-fit).
  __shared__ __align__(16) unsigned short s_W1[3*48*128];     // 36864 B
  __shared__ __align__(16) unsigned short s_Wih[144*64];      // 18432 B
  __shared__ __align__(16) unsigned short s_Whh[144*64];      // 18432 B
  volatile __shared__ int s_prog[8][16];                      // per-wave progress

  const int tid  = threadIdx.x;
  const int b    = blockIdx.x / NTI;
  const int tile = blockIdx.x % NTI;
  const int goff = tile * EFF - HALO;
  const int wave = tid >> 6;
  const int lane = tid & 63;
  const int quad = lane >> 4;
  const int l16  = lane & 15;
  const int col  = wave * 16 + l16;        // this lane's column (0..127)
  const int gt   = goff + col;             // global time of this column
  const size_t BXT = (size_t)BB * XD * T_DIM;

  // per-lane swizzled chunk offsets (shorts) for LDS weight reads
  const int swz = l16 & 7;
  const int ck0 = ((quad) ^ swz) * 8;
  const int ck1 = ((4 + quad) ^ swz) * 8;
  // message-matrix chunk (row l16, logical chunk quad, swizzled by l16&3)
  const int mck = ((quad ^ (l16 & 3)) * 8);

  // ---- one-time staging ----
  if (tid < 128) s_prog[tid >> 4][tid & 15] = 0;
  for (int i = tid; i < 2048; i += 512) s_Mmsg[i] = P.Mmsg[i];
  for (int i = tid; i < 144*16; i += 512) {
    int r = i >> 4, c = i & 15, cs = c ^ (r & 7);
    *(bf16x8*)&s_W1[r*128 + cs*8] = *(const bf16x8*)&P.W1b[r*128 + c*8];
  }
  for (int i = tid; i < 144*8; i += 512) {
    int r = i >> 3, c = i & 7, cs = c ^ (r & 7);
    *(bf16x8*)&s_Wih[r*64 + cs*8] = *(const bf16x8*)&P.Wihb[r*64 + c*8];
    *(bf16x8*)&s_Whh[r*64 + cs*8] = *(const bf16x8*)&P.Whhb[r*64 + c*8];
  }
  for (int i = tid; i < SC*HD; i += 512) {
    int c = i / HD, h = i - c*HD, g = goff + c;
    s_hy[c][h] = (g >= 0 && g < T_DIM) ? P.hy_b[((size_t)b*T_DIM + g)*HD + h] : 0;
  }
  for (int i = tid; i < (SC+2)*HP; i += 512) {
    int c = i / HP, h = i - c*HP;
    if (c == 0 || c == SC+1) { s_hx[0][c][h] = 0; s_hx[1][c][h] = 0; }
    else if (h < HD) {
      int g = goff + c - 1;
      float v = (g >= 0 && g < T_DIM) ? P.hx_src[((size_t)b*HD + h)*T_DIM + g] : 0.f;
      s_hx[0][c][h] = f2b(v);
      s_hx[1][c][h] = 0;                    // finite init: overrun reads at j=0
    } else {
      unsigned short v = (h == HD) ? (unsigned short)0x3F80 : 0;
      s_hx[0][c][h] = v; s_hx[1][c][h] = v;
    }
  }
  for (int i = tid; i < (SC+2)*12; i += 512) {
    int c = i / 12, x = i - c*12;
    float v = 0.f;
    if (c >= 1 && c <= SC && x < XD) {
      int g = goff + c - 1;
      if (g >= 0 && g < T_DIM) v = P.xs_src[((size_t)b*XD + x)*T_DIM + g];
    }
    s_xs[0][c][x] = v;
    if (c == 0 || c == SC+1) s_xs[1][c][x] = 0.f;
  }
  // per-lane fp32 hx carry + per-lane mconst (loop-invariant)
  float hcur[3][4];
  float mc0 = 0.f, mc1 = 0.f;
  {
    const bool v = (gt >= 0) && (gt < T_DIM);
    #pragma unroll
    for (int rt = 0; rt < 3; rt++)
      #pragma unroll
      for (int r = 0; r < 4; r++) {
        int h = rt*16 + quad*4 + r;
        hcur[rt][r] = v ? P.hx_src[((size_t)b*HD + h)*T_DIM + gt] : 0.f;
      }
    if (v) {
      mc0 = P.mconst[((size_t)b*XD + quad*2 + 0)*T_DIM + gt];
      mc1 = P.mconst[((size_t)b*XD + quad*2 + 1)*T_DIM + gt];
    }
  }
  __syncthreads();   // staging barrier (the ONLY block-wide barrier)

  // ---- register carries (post-barrier): hy frags (invariant) + center-hx frags
  bf16x8 hyb1 = ldg8(&s_hy[col][(quad & 1)*8]);
  bf16x8 hyb2 = ldg8(&s_hy[col][16 + quad*8]);
  bf16x8 ctr0 = ldg8(&s_hx[0][col+1][quad*8]);
  bf16x8 ctrg = ldg8(&s_hx[0][col+1][32 + quad*8]);  // quad3 overrun: finite x zero-weights

  const bool eff = (col >= HALO) && (col < HALO + EFF);
  const bool gtv = (gt >= 0) && (gt < T_DIM);
  const bool btile = (tile == 0) || (tile == NTI - 1);

  #pragma unroll 1
  for (int j = 0; j < FUSE; j++) {
    // ---- pairwise dataflow sync (replaces __syncthreads) ----
    if (j > 0) {
      if (wave > 0) { while (s_prog[wave-1][0] < j) {} }
      if (wave < 7) { while (s_prog[wave+1][0] < j) {} }
      __asm__ __volatile__("" ::: "memory");   // no LDS op crosses the spin
    }

    const int p = j & 1;
    const unsigned short (*hxP)[HP] = s_hx[p];
    unsigned short (*hxN)[HP] = s_hx[p ^ 1];
    const float (*xsP)[12] = s_xs[p];
    float (*xsN)[12] = s_xs[p ^ 1];
    const int k = P.k0 + j;
    float* out_k = P.out + BXT + (size_t)k * BXT;

    // ---- messages via MFMA ----
    const float* srcx = &xsP[col + ((quad == 0) ? 0 : (quad == 1) ? 2 : 1)][0];
    f32x4 xv0 = *(const f32x4*)&srcx[0];
    f32x4 xv1 = *(const f32x4*)&srcx[4];
    unsigned h0 = pk2(xv0[0], xv0[1]), h1 = pk2(xv0[2], xv0[3]);
    unsigned h2 = pk2(xv1[0], xv1[1]), h3 = pk2(xv1[2], xv1[3]);
    unsigned l0 = pk2(xv0[0] - b2fl(h0), xv0[1] - b2fh(h0));
    unsigned l1 = pk2(xv0[2] - b2fl(h1), xv0[3] - b2fh(h1));
    unsigned l2 = pk2(xv1[0] - b2fl(h2), xv1[1] - b2fh(h2));
    unsigned l3 = pk2(xv1[2] - b2fl(h3), xv1[3] - b2fh(h3));
    bf16x8 vh = (quad == 3) ? mk8(l0, l1, l2, l3) : mk8(h0, h1, h2, h3);
    bf16x8 vl = (quad < 2)  ? mk8(l0, l1, l2, l3) : mk8(0, 0, 0, 0);
    bf16x8 mAh = ldg8(s_Mmsg + (0*16 + l16)*32 + mck);
    bf16x8 mAl = ldg8(s_Mmsg + (1*16 + l16)*32 + mck);
    bf16x8 mBh = ldg8(s_Mmsg + (2*16 + l16)*32 + mck);
    bf16x8 mBl = ldg8(s_Mmsg + (3*16 + l16)*32 + mck);
    f32x4 accA = {0, 0, 0, 0};
    accA = MFMA16(mAh, vh, accA);
    accA = MFMA16(mAl, vh, accA);
    accA = MFMA16(mAh, vl, accA);
    f32x4 accB = {mc0, mc1, mc0, mc1};
    accB = MFMA16(mBh, vh, accB);
    accB = MFMA16(mBl, vh, accB);
    accB = MFMA16(mBh, vl, accB);
    // lane(q): accA = {mp[2q],mp[2q+1],mf[2q],mf[2q+1]}, accB = {my..., msum...}

    // ---- message B-frags (k96..127) via validated permlane gather ----
    bf16x8 b3e[3];
    #pragma unroll
    for (int e = 0; e < 3; e++) {
      unsigned d = (e == 0) ? pk2(accA[0], accA[1])
                 : (e == 1) ? pk2(accA[2], accA[3])
                            : pk2(accB[0], accB[1]);
      if (e == 0 && gt == 0) d = 0;            // mp mask at t=0
      if (e == 1 && gt == T_DIM - 1) d = 0;    // mf mask at t=T-1
      u32x2 s = __builtin_amdgcn_permlane32_swap(d, d, false, false);
      u32x2 a = __builtin_amdgcn_permlane16_swap(s[0], s[0], false, false);
      u32x2 g = __builtin_amdgcn_permlane16_swap(s[1], s[1], false, false);
      unsigned t0, t1, t2, t3;
      if (quad == 0)      { t0 = a[0]; t1 = a[1]; t2 = g[0]; t3 = g[1]; }
      else if (quad == 1) { t0 = 0x3F80u; t1 = 0; t2 = 0; t3 = 0; }
      else                { t0 = 0; t1 = 0; t2 = 0; t3 = 0; }
      b3e[e] = mk8(t0, t1, t2, t3);
    }

    // ---- msum to consumer layout (quad<2 holds msum[quad*4+r]) ----
    unsigned mA0, mB0, mA1, mB1;
    qswap(__float_as_uint(accB[2]), __float_as_uint(accB[3]), mA0, mB0);
    qswap(__float_as_uint(accB[3]), __float_as_uint(accB[2]), mA1, mB1);
    float msr0 = __uint_as_float(mA0), msr1 = __uint_as_float(mA1);
    float msr2 = __uint_as_float(mB0), msr3 = __uint_as_float(mB1);
    if (btile) {  // boundary tiles only: subtract masked message from msum
      unsigned pA0, pB0, pA1, pB1, fA0, fB0, fA1, fB1;
      qswap(__float_as_uint(accA[0]), __float_as_uint(accA[1]), pA0, pB0);
      qswap(__float_as_uint(accA[1]), __float_as_uint(accA[0]), pA1, pB1);
      qswap(__float_as_uint(accA[2]), __float_as_uint(accA[3]), fA0, fB0);
      qswap(__float_as_uint(accA[3]), __float_as_uint(accA[2]), fA1, fB1);
      if (gt == 0) {
        msr0 -= __uint_as_float(pA0); msr1 -= __uint_as_float(pA1);
        msr2 -= __uint_as_float(pB0); msr3 -= __uint_as_float(pB1);
      }
      if (gt == T_DIM - 1) {
        msr0 -= __uint_as_float(fA0); msr1 -= __uint_as_float(fA1);
        msr2 -= __uint_as_float(fB0); msr3 -= __uint_as_float(fB1);
      }
    }

    // ---- three edge MLPs (center-hx frags from carried registers) ----
    f32x4 agg[3] = {{0,0,0,0},{0,0,0,0},{0,0,0,0}};
    #pragma unroll
    for (int e = 0; e < 3; e++) {
      const unsigned short* W1e = s_W1 + e*48*128;
      const unsigned short* W2e = P.W2b + e*48*64;
      bf16x8 nbl, b2;
      if (e == 0)      { nbl = ldg8(&hxP[col][(quad & 1)*8]);   b2 = ldg8(&hxP[col][16 + quad*8]); }
      else if (e == 1) { nbl = ldg8(&hxP[col+2][(quad & 1)*8]); b2 = ldg8(&hxP[col+2][16 + quad*8]); }
      else             { nbl = hyb1; b2 = hyb2; }
      bf16x8 b0 = ctr0;
      bf16x8 b1 = (quad < 2) ? ctrg : nbl;
      bf16x8 b3 = b3e[e];
      f32x4 mid[3];
      #pragma unroll
      for (int rt = 0; rt < 3; rt++) {
        const unsigned short* wr = W1e + (rt*16 + l16)*128;
        f32x4 acc = {0,0,0,0};
        acc = MFMA16(ldg8(wr + ck0),      b0, acc);
        acc = MFMA16(ldg8(wr + ck1),      b1, acc);
        acc = MFMA16(ldg8(wr + 64 + ck0), b2, acc);
        acc = MFMA16(ldg8(wr + 64 + ck1), b3, acc);
        mid[rt] = acc;
      }
      // relu + in-register repack
      f32x4 rm0, rm1, rm2;
      #pragma unroll
      for (int r = 0; r < 4; r++) {
        rm0[r] = fmaxf(mid[0][r], 0.f);
        rm1[r] = fmaxf(mid[1][r], 0.f);
        rm2[r] = fmaxf(mid[2][r], 0.f);
      }
      bf16x8 c0, c1;
      frag48(rm0, rm1, rm2, quad, c0, c1);
      #pragma unroll
      for (int rt = 0; rt < 3; rt++) {
        const unsigned short* wr = W2e + (rt*16 + l16)*64;
        f32x4 acc = agg[rt];
        acc = MFMA16(ldg8(wr + quad*8),      c0, acc);
        acc = MFMA16(ldg8(wr + 32 + quad*8), c1, acc);
        agg[rt] = acc;
      }
    }

    // ---- GRU (agg repacked in-register; gh frags from carried registers) ----
    bf16x8 ga0, ga1;
    frag48(agg[0], agg[1], agg[2], quad, ga0, ga1);
    bf16x8 gh0 = ctr0;
    bf16x8 gh1 = ctrg;
    f32x4 rz[6], xn[3], hn[3];
    #pragma unroll
    for (int rt = 0; rt < 6; rt++) {
      const unsigned short* wi = s_Wih + (rt*16 + l16)*64;
      const unsigned short* wh = s_Whh + (rt*16 + l16)*64;
      f32x4 acc = {0,0,0,0};
      acc = MFMA16(ldg8(wi + ck0), ga0, acc);
      acc = MFMA16(ldg8(wi + ck1), ga1, acc);
      acc = MFMA16(ldg8(wh + ck0), gh0, acc);
      acc = MFMA16(ldg8(wh + ck1), gh1, acc);
      rz[rt] = acc;
    }
    #pragma unroll
    for (int rt = 0; rt < 3; rt++) {
      const unsigned short* wi = s_Wih + ((96 + rt*16) + l16)*64;
      const unsigned short* wh = s_Whh + ((96 + rt*16) + l16)*64;
      f32x4 a1 = {0,0,0,0}, a2 = {0,0,0,0};
      a1 = MFMA16(ldg8(wi + ck0), ga0, a1);
      a1 = MFMA16(ldg8(wi + ck1), ga1, a1);
      a2 = MFMA16(ldg8(wh + ck0), gh0, a2);
      a2 = MFMA16(ldg8(wh + ck1), gh1, a2);
      xn[rt] = a1; hn[rt] = a2;
    }
    #pragma unroll
    for (int rt = 0; rt < 3; rt++) {
      us4 pk;
      #pragma unroll
      for (int r = 0; r < 4; r++) {
        float rg = 1.f / (1.f + __expf(-rz[rt][r]));
        float zg = 1.f / (1.f + __expf(-rz[3+rt][r]));
        float na = xn[rt][r] + rg * hn[rt][r];
        float e2 = __expf(2.f * na);
        float nn = 1.f - 2.f / (e2 + 1.f);   // tanh
        float hnew = (1.f - zg) * nn + zg * hcur[rt][r];
        if (!gtv) hnew = 0.f;                // true zeros at sequence boundary
        hcur[rt][r] = hnew;
        pk[r] = f2b(hnew);
        if (j == FUSE-1 && eff && gtv) {
          int h = rt*16 + quad*4 + r;
          P.hx_dst[((size_t)b*HD + h)*T_DIM + gt] = hnew;
        }
      }
      *(us4*)&hxN[col+1][rt*16 + quad*4] = pk;   // publish for neighbor waves
    }

    // ---- decoder (hnew frags built in-register; they are next iter's ctr frags) ----
    f32x4 h0v, h1v, h2v;
    #pragma unroll
    for (int r = 0; r < 4; r++) { h0v[r] = hcur[0][r]; h1v[r] = hcur[1][r]; h2v[r] = hcur[2][r]; }
    bf16x8 d0, d1;
    frag48(h0v, h1v, h2v, quad, d0, d1);
    f32x4 dec = {0,0,0,0};
    dec = MFMA16(ldg8(P.Wdecb + l16*64 + quad*8),      d0, dec);
    dec = MFMA16(ldg8(P.Wdecb + l16*64 + 32 + quad*8), d1, dec);
    ctr0 = d0;   // carry: identical to next iteration's LDS read of hxN[col+1]
    ctrg = d1;
    if (quad < 2) {
      float msr[4] = {msr0, msr1, msr2, msr3};
      f32x4 xo;
      #pragma unroll
      for (int r = 0; r < 4; r++) {
        int x = quad*4 + r;
        float xnew = xsP[col+1][x] + GAMMA * (dec[r] + msr[r]);
        if (!gtv) xnew = 0.f;
        xo[r] = xnew;
        if (eff && gtv) {
          out_k[((size_t)b*XD + x)*T_DIM + gt] = xnew;
          if (k == NITER-1) P.out[((size_t)b*XD + x)*T_DIM + gt] = xnew;
        }
      }
      *(f32x4*)&xsN[col+1][quad*4] = xo;
    }

    // ---- publish progress: all this wave's LDS writes are complete ----
    __asm__ __volatile__("s_waitcnt lgkmcnt(0)" ::: "memory");
    if (lane == 0) s_prog[wave][0] = j + 1;
  }
}

// ---------------- host launch ----------------
extern "C" void kernel_launch(void* const* d_in, const int* in_sizes, int n_in,
                              void* d_out, int out_size, void* d_ws, size_t ws_size,
                              hipStream_t stream) {
  (void)in_sizes; (void)n_in; (void)out_size; (void)ws_size;
  const float* ys  = (const float*)d_in[0];
  const float* hx0 = (const float*)d_in[1];
  const float* F   = (const float*)d_in[2];
  const float* Hm  = (const float*)d_in[3];
  const float* Q   = (const float*)d_in[4];
  const float* R   = (const float*)d_in[5];

  float* out = (float*)d_out;
  float* ws  = (float*)d_ws;

  const size_t BXT = (size_t)BB * XD * T_DIM;   // 128000
  const size_t BHT = (size_t)BB * HD * T_DIM;   // 768000

  float* mats   = ws;                               // 512 f32
  unsigned short* Mmsg = (unsigned short*)(ws + 512); // 2048 bf16 = 1024 f32
  float* mconst = ws + 512 + 1024;                  // 128000
  float* xs0    = mconst + BXT;                     // 128000
  float* hxA    = xs0 + BXT;                        // 768000
  float* hxB    = hxA + BHT;                        // 768000
  unsigned short* hy_b  = (unsigned short*)(hxB + BHT);   // 768000
  unsigned short* W1b   = hy_b + BHT;                     // 18432
  unsigned short* W2b   = W1b + 3*48*128;                 // 9216
  unsigned short* Wihb  = W2b + 3*48*64;                  // 9216
  unsigned short* Whhb  = Wihb + 144*64;                  // 9216
  unsigned short* Wdecb = Whhb + 144*64;                  // 1024

  precompute_mats_kernel<<<1, 64, 0, stream>>>(F, Hm, Q, R, mats, Mmsg);
  precompute_bt_kernel<<<(BB*T_DIM + 255)/256, 256, 0, stream>>>(
      ys, (const float*)d_in[6], (const float*)d_in[7], Hm, mats, hy_b, mconst, xs0);

  WP wp;
  wp.W1[0] = (const float*)d_in[8];  wp.b1[0] = (const float*)d_in[9];
  wp.W2[0] = (const float*)d_in[10]; wp.b2[0] = (const float*)d_in[11];
  wp.W1[1] = (const float*)d_in[12]; wp.b1[1] = (const float*)d_in[13];
  wp.W2[1] = (const float*)d_in[14]; wp.b2[1] = (const float*)d_in[15];
  wp.W1[2] = (const float*)d_in[16]; wp.b1[2] = (const float*)d_in[17];
  wp.W2[2] = (const float*)d_in[18]; wp.b2[2] = (const float*)d_in[19];
  wp.Wih = (const float*)d_in[20]; wp.bih = (const float*)d_in[21];
  wp.Whh = (const float*)d_in[22]; wp.bhh = (const float*)d_in[23];
  wp.Wdec = (const float*)d_in[24]; wp.bdec = (const float*)d_in[25];
  wp.W1b = W1b; wp.W2b = W2b; wp.Wihb = Wihb; wp.Whhb = Whhb; wp.Wdecb = Wdecb;
  convert_weights_kernel<<<16, 256, 0, stream>>>(wp);

  FP P;
  P.Mmsg = Mmsg; P.mconst = mconst; P.hy_b = hy_b;
  P.W1b = W1b; P.W2b = W2b; P.Wihb = Wihb; P.Whhb = Whhb; P.Wdecb = Wdecb;
  P.out = out;

  for (int L = 0; L < NLNCH; L++) {
    int k0 = L * FUSE;
    P.k0 = k0;
    P.xs_src = (L == 0) ? xs0 : out + BXT + (size_t)(k0 - 1) * BXT;
    P.hx_src = (L == 0) ? hx0 : ((L & 1) ? hxA : hxB);
    P.hx_dst = (L & 1) ? hxB : hxA;
    fused_kernel<<<dim3(BB * NTI), dim3(512), 0, stream>>>(P);
  }
}

// Round 9
// 1696.198 us; speedup vs baseline: 1.0449x; 1.0449x over previous
//
#include <hip/hip_runtime.h>
#include <math.h>

// Problem constants (fixed by setup_inputs)
#define T_DIM 1000
#define BB    16
#define XD    8
#define YD    4
#define HD    48
#define NITER 200     // iterations (device scalar d_in[26], fixed)
#define GAMMA 1e-4f

// fused-scan geometry
#define HALO  25      // ghost columns each side
#define FUSE  25      // iterations fused per launch (valid shrink = HALO)
#define NLNCH 8       // FUSE*NLNCH == NITER
#define SC    128     // staged columns per block (8 waves x 16)
#define EFF   (SC - 2*HALO)   // 78 effective columns
#define NTI   13      // ceil(1000/EFF)
#define HP    56      // padded h-width (shorts) for [col][h] LDS tiles

typedef __attribute__((ext_vector_type(8))) short bf16x8;
typedef __attribute__((ext_vector_type(4))) float f32x4;
typedef __attribute__((ext_vector_type(4))) unsigned short us4;
typedef __attribute__((ext_vector_type(2))) unsigned u32x2;
typedef __attribute__((ext_vector_type(4))) unsigned u32x4;

#define MFMA16(a,b,c) __builtin_amdgcn_mfma_f32_16x16x32_bf16((a),(b),(c),0,0,0)

__device__ inline unsigned short f2b(float x) {
  union { float f; unsigned u; } v; v.f = x;
  unsigned r = (v.u + 0x7FFFu + ((v.u >> 16) & 1u)) >> 16;
  return (unsigned short)r;
}
__device__ inline float b2fl(unsigned p) {  // low bf16 of a packed pair -> f32
  union { unsigned u; float f; } v; v.u = p << 16; return v.f;
}
__device__ inline float b2fh(unsigned p) {  // high bf16 of a packed pair -> f32
  union { unsigned u; float f; } v; v.u = p & 0xFFFF0000u; return v.f;
}
__device__ inline bf16x8 ldg8(const unsigned short* p) { return *(const bf16x8*)p; }
// HW packed f32->bf16 convert (RNE, bit-identical to f2b for finite values).
// Replaces the 3-4-op bit-trick per value: ~350 VALU insts/wave/iter deleted.
// (m240's caveat targeted compiler-fusable scalar casts; our baseline was a
// bit-trick the compiler cannot fuse, so this is a strict win.)
__device__ inline unsigned cvtpk(float a, float b) {
  unsigned r;
  asm("v_cvt_pk_bf16_f32 %0, %1, %2" : "=v"(r) : "v"(a), "v"(b));
  return r;
}
__device__ inline unsigned pk2(float a, float b) {   // cold paths only
  return (unsigned)f2b(a) | ((unsigned)f2b(b) << 16);
}
__device__ inline bf16x8 mk8(unsigned a, unsigned b, unsigned c, unsigned d) {
  union { u32x4 u; bf16x8 v; } t; t.u[0]=a; t.u[1]=b; t.u[2]=c; t.u[3]=d; return t.v;
}
// 4-lane quad exchange (l16 preserved), VALIDATED mapping (R4-R8 passed):
// qswap(x0,x1) at quad q: A = x_{q>>1}@quad 2(q&1), B = x_{q>>1}@quad 2(q&1)+1.
__device__ inline void qswap(unsigned x0, unsigned x1, unsigned &A, unsigned &B) {
  u32x2 s = __builtin_amdgcn_permlane32_swap(x0, x1, false, false);
  u32x2 t = __builtin_amdgcn_permlane16_swap(s[0], s[1], false, false);
  A = t[0]; B = t[1];
}
// Redistribute 12 f32 rows/lane (C-layout) into MFMA B-frags c0 (k0..31) and
// c1 (k32..63; k48=bias 1.0). Bit-identical to an LDS round-trip.
__device__ inline void frag48(const f32x4 m0, const f32x4 m1, const f32x4 m2,
                              int quad, bf16x8 &c0, bf16x8 &c1) {
  unsigned p00 = cvtpk(m0[0], m0[1]), p01 = cvtpk(m0[2], m0[3]);
  unsigned p10 = cvtpk(m1[0], m1[1]), p11 = cvtpk(m1[2], m1[3]);
  unsigned p20 = cvtpk(m2[0], m2[1]), p21 = cvtpk(m2[2], m2[3]);
  unsigned A0,B0,A1,B1,A2,B2,A3,B3;
  qswap(p00, p10, A0, B0);
  qswap(p01, p11, A1, B1);
  qswap(p20, p20, A2, B2);
  qswap(p21, p21, A3, B3);
  c0 = mk8(A0, A1, B0, B1);
  unsigned t0, t1, t2, t3;
  if (quad < 2)       { t0 = A2; t1 = A3; t2 = B2; t3 = B3; }
  else if (quad == 2) { t0 = 0x3F80u; t1 = 0; t2 = 0; t3 = 0; }
  else                { t0 = 0; t1 = 0; t2 = 0; t3 = 0; }
  c1 = mk8(t0, t1, t2, t3);
}

// ---------------- precompute: inverses + fused mats + message matrices ----------------
// mats: Qi[0..63], QiF[64..127], FtQi[128..191], FtQiF[192..255], HtRi[256..287], HtRiH[288..351]
// Mmsg[4][16][32] bf16 (0=A_hi,1=A_lo,2=B_hi,3=B_lo), 16B chunks XOR-swizzled by row&3.
__global__ __launch_bounds__(64) void precompute_mats_kernel(
    const float* __restrict__ F, const float* __restrict__ Hm,
    const float* __restrict__ Q, const float* __restrict__ R,
    float* __restrict__ mats, unsigned short* __restrict__ Mmsg)
{
  __shared__ float sQi[64], sRi[16], sF[64], sH[32], sFtQi[64], sHtRi[32];
  __shared__ float sQiF[64], sFtQiF[64], sHtRiH[64];
  const int t = threadIdx.x;
  if (t < 64) sF[t] = F[t];
  if (t < 32) sH[t] = Hm[t];
  {
    float col[8];
    #pragma unroll
    for (int i = 0; i < 8; i++)
      col[i] = (t < 8) ? Q[i*8 + t] : ((t < 16 && i == t - 8) ? 1.f : 0.f);
    #pragma unroll
    for (int c = 0; c < 8; c++) {
      float Mcc = __shfl(col[c], c);
      float f[8];
      #pragma unroll
      for (int r = 0; r < 8; r++) f[r] = __shfl(col[r], c);
      float newc = col[c] / Mcc;
      col[c] = newc;
      #pragma unroll
      for (int r = 0; r < 8; r++) if (r != c) col[r] -= f[r] * newc;
    }
    if (t >= 8 && t < 16) {
      #pragma unroll
      for (int i = 0; i < 8; i++) sQi[i*8 + (t - 8)] = col[i];
    }
  }
  {
    float col[4];
    #pragma unroll
    for (int i = 0; i < 4; i++)
      col[i] = (t < 4) ? R[i*4 + t] : ((t < 8 && i == t - 4) ? 1.f : 0.f);
    #pragma unroll
    for (int c = 0; c < 4; c++) {
      float Mcc = __shfl(col[c], c);
      float f[4];
      #pragma unroll
      for (int r = 0; r < 4; r++) f[r] = __shfl(col[r], c);
      float newc = col[c] / Mcc;
      col[c] = newc;
      #pragma unroll
      for (int r = 0; r < 4; r++) if (r != c) col[r] -= f[r] * newc;
    }
    if (t >= 4 && t < 8) {
      #pragma unroll
      for (int i = 0; i < 4; i++) sRi[i*4 + (t - 4)] = col[i];
    }
  }
  __syncthreads();
  const int i = t >> 3, j = t & 7;
  mats[t] = sQi[t];
  { float s = 0.f; for (int k = 0; k < 8; k++) s += sQi[i*8+k] * sF[k*8+j]; mats[64 + t] = s; sQiF[t] = s; }
  { float s = 0.f; for (int k = 0; k < 8; k++) s += sF[k*8+i] * sQi[k*8+j]; mats[128 + t] = s; sFtQi[t] = s; }
  if (t < 32) {
    int ii = t >> 2, z = t & 3;
    float s = 0.f; for (int y = 0; y < 4; y++) s += sH[y*8+ii] * sRi[y*4+z];
    mats[256 + t] = s; sHtRi[t] = s;
  }
  __syncthreads();
  { float s = 0.f; for (int k = 0; k < 8; k++) s += sFtQi[i*8+k] * sF[k*8+j]; mats[192 + t] = s; sFtQiF[t] = s; }
  { float s = 0.f; for (int z = 0; z < 4; z++) s += sHtRi[i*4+z] * sH[z*8+j]; mats[288 + t] = s; sHtRiH[t] = s; }
  __syncthreads();
  for (int ii = t; ii < 2048; ii += 64) {
    int m = ii >> 9;            // 0..3: A_hi, A_lo, B_hi, B_lo
    int row = (ii >> 5) & 15;
    int kk = ii & 31;
    int g = m >> 1, hilo = m & 1;
    int q = row >> 2, r = row & 3, x = 2*q + (r & 1);
    int kb = kk >> 3, jj = kk & 7;
    float c = 0.f;
    if (g == 0) {
      if (r < 2) c = (kb == 0) ? sQiF[x*8+jj] : (kb >= 2) ? -sQi[x*8+jj] : 0.f;
      else       c = (kb == 1) ? sFtQi[x*8+jj] : (kb >= 2) ? -sFtQiF[x*8+jj] : 0.f;
    } else {
      if (r < 2) c = (kb >= 2) ? -sHtRiH[x*8+jj] : 0.f;
      else       c = (kb == 0) ? sQiF[x*8+jj] : (kb == 1) ? sFtQi[x*8+jj]
                   : -(sQi[x*8+jj] + sFtQiF[x*8+jj] + sHtRiH[x*8+jj]);
    }
    unsigned short hv = f2b(c);
    unsigned short out = hv;
    if (hilo) out = f2b(c - b2fl((unsigned)hv));
    Mmsg[(m*16 + row)*32 + ((kb ^ (row & 3)) * 8) + jj] = out;
  }
}

// ---------------- precompute per (b,t): hy (bf16), xs0, mconst ----------------
__global__ void precompute_bt_kernel(const float* __restrict__ ys,
                                     const float* __restrict__ W_hy, const float* __restrict__ b_hy,
                                     const float* __restrict__ Hm, const float* __restrict__ mats,
                                     unsigned short* __restrict__ hy_b,
                                     float* __restrict__ mconst, float* __restrict__ xs0)
{
  int idx = blockIdx.x * 256 + threadIdx.x;
  if (idx >= BB * T_DIM) return;
  int b = idx / T_DIM, t = idx - b * T_DIM;
  float yy[YD];
  #pragma unroll
  for (int y = 0; y < YD; y++) yy[y] = ys[(b*T_DIM + t)*YD + y];
  #pragma unroll 4
  for (int h = 0; h < HD; h++) {
    float s = b_hy[h];
    #pragma unroll
    for (int y = 0; y < YD; y++) s += W_hy[h*YD+y] * yy[y];
    hy_b[(b*T_DIM + t)*HD + h] = f2b(s);
  }
  const float* HtRi = mats + 256;
  #pragma unroll
  for (int x = 0; x < XD; x++) {
    float s0 = 0.f, s1 = 0.f;
    #pragma unroll
    for (int y = 0; y < YD; y++) {
      s0 += Hm[y*XD + x] * yy[y];
      s1 += HtRi[x*YD + y] * yy[y];
    }
    xs0[(b*XD + x)*T_DIM + t]    = s0;
    mconst[(b*XD + x)*T_DIM + t] = s1;
  }
}

// ---------------- weight conversion to padded bf16 with bias folded into K ----------------
struct WP {
  const float *W1[3], *b1[3], *W2[3], *b2[3], *Wih, *bih, *Whh, *bhh, *Wdec, *bdec;
  unsigned short *W1b, *W2b, *Wihb, *Whhb, *Wdecb;
};
__global__ void convert_weights_kernel(WP p) {
  int idx = blockIdx.x * 256 + threadIdx.x;
  int stride = gridDim.x * 256;
  // W1b: [3][48][128] : cols 0..103 = W1, col 104 = b1, rest 0
  for (int i = idx; i < 3*48*128; i += stride) {
    int e = i / (48*128), r = (i / 128) % 48, k = i & 127;
    float v = (k < 104) ? p.W1[e][r*104 + k] : (k == 104) ? p.b1[e][r] : 0.f;
    p.W1b[i] = (k <= 104) ? f2b(v) : 0;
  }
  // W2b: [3][48][64] : cols 0..47 = W2, col 48 = b2
  for (int i = idx; i < 3*48*64; i += stride) {
    int e = i / (48*64), r = (i / 64) % 48, k = i & 63;
    float v = (k < HD) ? p.W2[e][r*HD + k] : (k == HD) ? p.b2[e][r] : 0.f;
    p.W2b[i] = (k <= HD) ? f2b(v) : 0;
  }
  // Wihb/Whhb: [144][64] : col 48 = bias
  for (int i = idx; i < 144*64; i += stride) {
    int r = i >> 6, k = i & 63;
    p.Wihb[i] = (k < HD) ? f2b(p.Wih[r*HD + k]) : (k == HD) ? f2b(p.bih[r]) : 0;
    p.Whhb[i] = (k < HD) ? f2b(p.Whh[r*HD + k]) : (k == HD) ? f2b(p.bhh[r]) : 0;
  }
  // Wdecb: [16][64]
  for (int i = idx; i < 16*64; i += stride) {
    int r = i >> 6, k = i & 63;
    unsigned short v = 0;
    if (r < XD) {
      if (k < HD) v = f2b(p.Wdec[r*HD + k]);
      else if (k == HD) v = f2b(p.bdec[r]);
    }
    p.Wdecb[i] = v;
  }
}

// ---------------- fused multi-iteration scan kernel ----------------
struct FP {
  const unsigned short* Mmsg;
  const float* mconst;
  const unsigned short* hy_b;
  const unsigned short *W1b, *W2b, *Wihb, *Whhb, *Wdecb;
  const float *xs_src, *hx_src;   // state after iteration k0-1
  float* hx_dst;                  // state after iteration k0+FUSE-1
  float* out;                     // [BXT final][NITER][B][XD][T]
  int k0;
};

__global__ __launch_bounds__(512, 2)
void fused_kernel(FP P)
{
  // R9: all hot-loop f32->bf16 packing via v_cvt_pk_bf16_f32 (1 inst per pair
  // vs 7-8 for the f2b bit-trick; RNE both -> bit-identical). Mmsg fragments
  // (4 x bf16x8 = 16 VGPR, loop-invariant) hoisted to registers -- small
  // invariant carries survive the 128-VGPR cap (hyb/hcur precedent); only
  // the 96-144-reg arrays spilled (R2/R3/R5).
  __shared__ __align__(16) unsigned short s_hx[2][SC+2][HP];  // bf16 hx, dbuf, rows=col+1, col 48=1.0(bias)
  __shared__ __align__(16) unsigned short s_hy[SC][HD];       // bf16 hy (const)
  __shared__ __align__(16) float s_xs[2][SC+2][12];           // fp32 xs, dbuf
  __shared__ __align__(16) unsigned short s_Mmsg[2048];       // message matrices (4x16x32)
  // bf16 weights staged in LDS once per block; 16B chunk c of row r stored at
  // chunk c^(r&7). W2b + Wdecb stay global (L1-fit).
  __shared__ __align__(16) unsigned short s_W1[3*48*128];     // 36864 B
  __shared__ __align__(16) unsigned short s_Wih[144*64];      // 18432 B
  __shared__ __align__(16) unsigned short s_Whh[144*64];      // 18432 B
  volatile __shared__ int s_prog[8][16];                      // per-wave progress

  const int tid  = threadIdx.x;
  const int b    = blockIdx.x / NTI;
  const int tile = blockIdx.x % NTI;
  const int goff = tile * EFF - HALO;
  const int wave = tid >> 6;
  const int lane = tid & 63;
  const int quad = lane >> 4;
  const int l16  = lane & 15;
  const int col  = wave * 16 + l16;        // this lane's column (0..127)
  const int gt   = goff + col;             // global time of this column
  const size_t BXT = (size_t)BB * XD * T_DIM;

  // per-lane swizzled chunk offsets (shorts) for LDS weight reads
  const int swz = l16 & 7;
  const int ck0 = ((quad) ^ swz) * 8;
  const int ck1 = ((4 + quad) ^ swz) * 8;
  // message-matrix chunk (row l16, logical chunk quad, swizzled by l16&3)
  const int mck = ((quad ^ (l16 & 3)) * 8);

  // ---- one-time staging ----
  if (tid < 128) s_prog[tid >> 4][tid & 15] = 0;
  for (int i = tid; i < 2048; i += 512) s_Mmsg[i] = P.Mmsg[i];
  for (int i = tid; i < 144*16; i += 512) {
    int r = i >> 4, c = i & 15, cs = c ^ (r & 7);
    *(bf16x8*)&s_W1[r*128 + cs*8] = *(const bf16x8*)&P.W1b[r*128 + c*8];
  }
  for (int i = tid; i < 144*8; i += 512) {
    int r = i >> 3, c = i & 7, cs = c ^ (r & 7);
    *(bf16x8*)&s_Wih[r*64 + cs*8] = *(const bf16x8*)&P.Wihb[r*64 + c*8];
    *(bf16x8*)&s_Whh[r*64 + cs*8] = *(const bf16x8*)&P.Whhb[r*64 + c*8];
  }
  for (int i = tid; i < SC*HD; i += 512) {
    int c = i / HD, h = i - c*HD, g = goff + c;
    s_hy[c][h] = (g >= 0 && g < T_DIM) ? P.hy_b[((size_t)b*T_DIM + g)*HD + h] : 0;
  }
  for (int i = tid; i < (SC+2)*HP; i += 512) {
    int c = i / HP, h = i - c*HP;
    if (c == 0 || c == SC+1) { s_hx[0][c][h] = 0; s_hx[1][c][h] = 0; }
    else if (h < HD) {
      int g = goff + c - 1;
      float v = (g >= 0 && g < T_DIM) ? P.hx_src[((size_t)b*HD + h)*T_DIM + g] : 0.f;
      s_hx[0][c][h] = f2b(v);
      s_hx[1][c][h] = 0;                    // finite init: overrun reads at j=0
    } else {
      unsigned short v = (h == HD) ? (unsigned short)0x3F80 : 0;
      s_hx[0][c][h] = v; s_hx[1][c][h] = v;
    }
  }
  for (int i = tid; i < (SC+2)*12; i += 512) {
    int c = i / 12, x = i - c*12;
    float v = 0.f;
    if (c >= 1 && c <= SC && x < XD) {
      int g = goff + c - 1;
      if (g >= 0 && g < T_DIM) v = P.xs_src[((size_t)b*XD + x)*T_DIM + g];
    }
    s_xs[0][c][x] = v;
    if (c == 0 || c == SC+1) s_xs[1][c][x] = 0.f;
  }
  // per-lane fp32 hx carry + per-lane mconst (loop-invariant)
  float hcur[3][4];
  float mc0 = 0.f, mc1 = 0.f;
  {
    const bool v = (gt >= 0) && (gt < T_DIM);
    #pragma unroll
    for (int rt = 0; rt < 3; rt++)
      #pragma unroll
      for (int r = 0; r < 4; r++) {
        int h = rt*16 + quad*4 + r;
        hcur[rt][r] = v ? P.hx_src[((size_t)b*HD + h)*T_DIM + gt] : 0.f;
      }
    if (v) {
      mc0 = P.mconst[((size_t)b*XD + quad*2 + 0)*T_DIM + gt];
      mc1 = P.mconst[((size_t)b*XD + quad*2 + 1)*T_DIM + gt];
    }
  }
  __syncthreads();   // staging barrier (the ONLY block-wide barrier)

  // ---- register carries (post-barrier): hy frags + center-hx frags + Mmsg frags
  bf16x8 hyb1 = ldg8(&s_hy[col][(quad & 1)*8]);
  bf16x8 hyb2 = ldg8(&s_hy[col][16 + quad*8]);
  bf16x8 ctr0 = ldg8(&s_hx[0][col+1][quad*8]);
  bf16x8 ctrg = ldg8(&s_hx[0][col+1][32 + quad*8]);  // quad3 overrun: finite x zero-weights
  bf16x8 mAh = ldg8(s_Mmsg + (0*16 + l16)*32 + mck); // loop-invariant message mats
  bf16x8 mAl = ldg8(s_Mmsg + (1*16 + l16)*32 + mck);
  bf16x8 mBh = ldg8(s_Mmsg + (2*16 + l16)*32 + mck);
  bf16x8 mBl = ldg8(s_Mmsg + (3*16 + l16)*32 + mck);

  const bool eff = (col >= HALO) && (col < HALO + EFF);
  const bool gtv = (gt >= 0) && (gt < T_DIM);
  const bool btile = (tile == 0) || (tile == NTI - 1);

  #pragma unroll 1
  for (int j = 0; j < FUSE; j++) {
    // ---- pairwise dataflow sync (replaces __syncthreads) ----
    if (j > 0) {
      if (wave > 0) { while (s_prog[wave-1][0] < j) {} }
      if (wave < 7) { while (s_prog[wave+1][0] < j) {} }
      __asm__ __volatile__("" ::: "memory");   // no LDS op crosses the spin
    }

    const int p = j & 1;
    const unsigned short (*hxP)[HP] = s_hx[p];
    unsigned short (*hxN)[HP] = s_hx[p ^ 1];
    const float (*xsP)[12] = s_xs[p];
    float (*xsN)[12] = s_xs[p ^ 1];
    const int k = P.k0 + j;
    float* out_k = P.out + BXT + (size_t)k * BXT;

    // ---- messages via MFMA ----
    const float* srcx = &xsP[col + ((quad == 0) ? 0 : (quad == 1) ? 2 : 1)][0];
    f32x4 xv0 = *(const f32x4*)&srcx[0];
    f32x4 xv1 = *(const f32x4*)&srcx[4];
    unsigned h0 = cvtpk(xv0[0], xv0[1]), h1 = cvtpk(xv0[2], xv0[3]);
    unsigned h2 = cvtpk(xv1[0], xv1[1]), h3 = cvtpk(xv1[2], xv1[3]);
    unsigned l0 = cvtpk(xv0[0] - b2fl(h0), xv0[1] - b2fh(h0));
    unsigned l1 = cvtpk(xv0[2] - b2fl(h1), xv0[3] - b2fh(h1));
    unsigned l2 = cvtpk(xv1[0] - b2fl(h2), xv1[1] - b2fh(h2));
    unsigned l3 = cvtpk(xv1[2] - b2fl(h3), xv1[3] - b2fh(h3));
    bf16x8 vh = (quad == 3) ? mk8(l0, l1, l2, l3) : mk8(h0, h1, h2, h3);
    bf16x8 vl = (quad < 2)  ? mk8(l0, l1, l2, l3) : mk8(0, 0, 0, 0);
    f32x4 accA = {0, 0, 0, 0};
    accA = MFMA16(mAh, vh, accA);
    accA = MFMA16(mAl, vh, accA);
    accA = MFMA16(mAh, vl, accA);
    f32x4 accB = {mc0, mc1, mc0, mc1};
    accB = MFMA16(mBh, vh, accB);
    accB = MFMA16(mBl, vh, accB);
    accB = MFMA16(mBh, vl, accB);
    // lane(q): accA = {mp[2q],mp[2q+1],mf[2q],mf[2q+1]}, accB = {my..., msum...}

    // ---- message B-frags (k96..127) via validated permlane gather ----
    bf16x8 b3e[3];
    #pragma unroll
    for (int e = 0; e < 3; e++) {
      unsigned d = (e == 0) ? cvtpk(accA[0], accA[1])
                 : (e == 1) ? cvtpk(accA[2], accA[3])
                            : cvtpk(accB[0], accB[1]);
      if (e == 0 && gt == 0) d = 0;            // mp mask at t=0
      if (e == 1 && gt == T_DIM - 1) d = 0;    // mf mask at t=T-1
      u32x2 s = __builtin_amdgcn_permlane32_swap(d, d, false, false);
      u32x2 a = __builtin_amdgcn_permlane16_swap(s[0], s[0], false, false);
      u32x2 g = __builtin_amdgcn_permlane16_swap(s[1], s[1], false, false);
      unsigned t0, t1, t2, t3;
      if (quad == 0)      { t0 = a[0]; t1 = a[1]; t2 = g[0]; t3 = g[1]; }
      else if (quad == 1) { t0 = 0x3F80u; t1 = 0; t2 = 0; t3 = 0; }
      else                { t0 = 0; t1 = 0; t2 = 0; t3 = 0; }
      b3e[e] = mk8(t0, t1, t2, t3);
    }

    // ---- msum to consumer layout (quad<2 holds msum[quad*4+r]) ----
    unsigned mA0, mB0, mA1, mB1;
    qswap(__float_as_uint(accB[2]), __float_as_uint(accB[3]), mA0, mB0);
    qswap(__float_as_uint(accB[3]), __float_as_uint(accB[2]), mA1, mB1);
    float msr0 = __uint_as_float(mA0), msr1 = __uint_as_float(mA1);
    float msr2 = __uint_as_float(mB0), msr3 = __uint_as_float(mB1);
    if (btile) {  // boundary tiles only: subtract masked message from msum
      unsigned pA0, pB0, pA1, pB1, fA0, fB0, fA1, fB1;
      qswap(__float_as_uint(accA[0]), __float_as_uint(accA[1]), pA0, pB0);
      qswap(__float_as_uint(accA[1]), __float_as_uint(accA[0]), pA1, pB1);
      qswap(__float_as_uint(accA[2]), __float_as_uint(accA[3]), fA0, fB0);
      qswap(__float_as_uint(accA[3]), __float_as_uint(accA[2]), fA1, fB1);
      if (gt == 0) {
        msr0 -= __uint_as_float(pA0); msr1 -= __uint_as_float(pA1);
        msr2 -= __uint_as_float(pB0); msr3 -= __uint_as_float(pB1);
      }
      if (gt == T_DIM - 1) {
        msr0 -= __uint_as_float(fA0); msr1 -= __uint_as_float(fA1);
        msr2 -= __uint_as_float(fB0); msr3 -= __uint_as_float(fB1);
      }
    }

    // ---- three edge MLPs (center-hx frags from carried registers) ----
    f32x4 agg[3] = {{0,0,0,0},{0,0,0,0},{0,0,0,0}};
    #pragma unroll
    for (int e = 0; e < 3; e++) {
      const unsigned short* W1e = s_W1 + e*48*128;
      const unsigned short* W2e = P.W2b + e*48*64;
      bf16x8 nbl, b2;
      if (e == 0)      { nbl = ldg8(&hxP[col][(quad & 1)*8]);   b2 = ldg8(&hxP[col][16 + quad*8]); }
      else if (e == 1) { nbl = ldg8(&hxP[col+2][(quad & 1)*8]); b2 = ldg8(&hxP[col+2][16 + quad*8]); }
      else             { nbl = hyb1; b2 = hyb2; }
      bf16x8 b0 = ctr0;
      bf16x8 b1 = (quad < 2) ? ctrg : nbl;
      bf16x8 b3 = b3e[e];
      f32x4 mid[3];
      #pragma unroll
      for (int rt = 0; rt < 3; rt++) {
        const unsigned short* wr = W1e + (rt*16 + l16)*128;
        f32x4 acc = {0,0,0,0};
        acc = MFMA16(ldg8(wr + ck0),      b0, acc);
        acc = MFMA16(ldg8(wr + ck1),      b1, acc);
        acc = MFMA16(ldg8(wr + 64 + ck0), b2, acc);
        acc = MFMA16(ldg8(wr + 64 + ck1), b3, acc);
        mid[rt] = acc;
      }
      // relu + in-register repack
      f32x4 rm0, rm1, rm2;
      #pragma unroll
      for (int r = 0; r < 4; r++) {
        rm0[r] = fmaxf(mid[0][r], 0.f);
        rm1[r] = fmaxf(mid[1][r], 0.f);
        rm2[r] = fmaxf(mid[2][r], 0.f);
      }
      bf16x8 c0, c1;
      frag48(rm0, rm1, rm2, quad, c0, c1);
      #pragma unroll
      for (int rt = 0; rt < 3; rt++) {
        const unsigned short* wr = W2e + (rt*16 + l16)*64;
        f32x4 acc = agg[rt];
        acc = MFMA16(ldg8(wr + quad*8),      c0, acc);
        acc = MFMA16(ldg8(wr + 32 + quad*8), c1, acc);
        agg[rt] = acc;
      }
    }

    // ---- GRU (agg repacked in-register; gh frags from carried registers) ----
    bf16x8 ga0, ga1;
    frag48(agg[0], agg[1], agg[2], quad, ga0, ga1);
    bf16x8 gh0 = ctr0;
    bf16x8 gh1 = ctrg;
    f32x4 rz[6], xn[3], hn[3];
    #pragma unroll
    for (int rt = 0; rt < 6; rt++) {
      const unsigned short* wi = s_Wih + (rt*16 + l16)*64;
      const unsigned short* wh = s_Whh + (rt*16 + l16)*64;
      f32x4 acc = {0,0,0,0};
      acc = MFMA16(ldg8(wi + ck0), ga0, acc);
      acc = MFMA16(ldg8(wi + ck1), ga1, acc);
      acc = MFMA16(ldg8(wh + ck0), gh0, acc);
      acc = MFMA16(ldg8(wh + ck1), gh1, acc);
      rz[rt] = acc;
    }
    #pragma unroll
    for (int rt = 0; rt < 3; rt++) {
      const unsigned short* wi = s_Wih + ((96 + rt*16) + l16)*64;
      const unsigned short* wh = s_Whh + ((96 + rt*16) + l16)*64;
      f32x4 a1 = {0,0,0,0}, a2 = {0,0,0,0};
      a1 = MFMA16(ldg8(wi + ck0), ga0, a1);
      a1 = MFMA16(ldg8(wi + ck1), ga1, a1);
      a2 = MFMA16(ldg8(wh + ck0), gh0, a2);
      a2 = MFMA16(ldg8(wh + ck1), gh1, a2);
      xn[rt] = a1; hn[rt] = a2;
    }
    #pragma unroll
    for (int rt = 0; rt < 3; rt++) {
      #pragma unroll
      for (int r = 0; r < 4; r++) {
        float rg = 1.f / (1.f + __expf(-rz[rt][r]));
        float zg = 1.f / (1.f + __expf(-rz[3+rt][r]));
        float na = xn[rt][r] + rg * hn[rt][r];
        float e2 = __expf(2.f * na);
        float nn = 1.f - 2.f / (e2 + 1.f);   // tanh
        float hnew = (1.f - zg) * nn + zg * hcur[rt][r];
        if (!gtv) hnew = 0.f;                // true zeros at sequence boundary
        hcur[rt][r] = hnew;
        if (j == FUSE-1 && eff && gtv) {
          int h = rt*16 + quad*4 + r;
          P.hx_dst[((size_t)b*HD + h)*T_DIM + gt] = hnew;
        }
      }
      unsigned w0 = cvtpk(hcur[rt][0], hcur[rt][1]);
      unsigned w1 = cvtpk(hcur[rt][2], hcur[rt][3]);
      union { unsigned u[2]; us4 v; } pw; pw.u[0] = w0; pw.u[1] = w1;
      *(us4*)&hxN[col+1][rt*16 + quad*4] = pw.v;   // publish for neighbor waves
    }

    // ---- decoder (hnew frags built in-register; they are next iter's ctr frags) ----
    f32x4 h0v, h1v, h2v;
    #pragma unroll
    for (int r = 0; r < 4; r++) { h0v[r] = hcur[0][r]; h1v[r] = hcur[1][r]; h2v[r] = hcur[2][r]; }
    bf16x8 d0, d1;
    frag48(h0v, h1v, h2v, quad, d0, d1);
    f32x4 dec = {0,0,0,0};
    dec = MFMA16(ldg8(P.Wdecb + l16*64 + quad*8),      d0, dec);
    dec = MFMA16(ldg8(P.Wdecb + l16*64 + 32 + quad*8), d1, dec);
    ctr0 = d0;   // carry: identical to next iteration's LDS read of hxN[col+1]
    ctrg = d1;
    if (quad < 2) {
      float msr[4] = {msr0, msr1, msr2, msr3};
      f32x4 xo;
      #pragma unroll
      for (int r = 0; r < 4; r++) {
        int x = quad*4 + r;
        float xnew = xsP[col+1][x] + GAMMA * (dec[r] + msr[r]);
        if (!gtv) xnew = 0.f;
        xo[r] = xnew;
        if (eff && gtv) {
          out_k[((size_t)b*XD + x)*T_DIM + gt] = xnew;
          if (k == NITER-1) P.out[((size_t)b*XD + x)*T_DIM + gt] = xnew;
        }
      }
      *(f32x4*)&xsN[col+1][quad*4] = xo;
    }

    // ---- publish progress: all this wave's LDS writes are complete ----
    __asm__ __volatile__("s_waitcnt lgkmcnt(0)" ::: "memory");
    if (lane == 0) s_prog[wave][0] = j + 1;
  }
}

// ---------------- host launch ----------------
extern "C" void kernel_launch(void* const* d_in, const int* in_sizes, int n_in,
                              void* d_out, int out_size, void* d_ws, size_t ws_size,
                              hipStream_t stream) {
  (void)in_sizes; (void)n_in; (void)out_size; (void)ws_size;
  const float* ys  = (const float*)d_in[0];
  const float* hx0 = (const float*)d_in[1];
  const float* F   = (const float*)d_in[2];
  const float* Hm  = (const float*)d_in[3];
  const float* Q   = (const float*)d_in[4];
  const float* R   = (const float*)d_in[5];

  float* out = (float*)d_out;
  float* ws  = (float*)d_ws;

  const size_t BXT = (size_t)BB * XD * T_DIM;   // 128000
  const size_t BHT = (size_t)BB * HD * T_DIM;   // 768000

  float* mats   = ws;                               // 512 f32
  unsigned short* Mmsg = (unsigned short*)(ws + 512); // 2048 bf16 = 1024 f32
  float* mconst = ws + 512 + 1024;                  // 128000
  float* xs0    = mconst + BXT;                     // 128000
  float* hxA    = xs0 + BXT;                        // 768000
  float* hxB    = hxA + BHT;                        // 768000
  unsigned short* hy_b  = (unsigned short*)(hxB + BHT);   // 768000
  unsigned short* W1b   = hy_b + BHT;                     // 18432
  unsigned short* W2b   = W1b + 3*48*128;                 // 9216
  unsigned short* Wihb  = W2b + 3*48*64;                  // 9216
  unsigned short* Whhb  = Wihb + 144*64;                  // 9216
  unsigned short* Wdecb = Whhb + 144*64;                  // 1024

  precompute_mats_kernel<<<1, 64, 0, stream>>>(F, Hm, Q, R, mats, Mmsg);
  precompute_bt_kernel<<<(BB*T_DIM + 255)/256, 256, 0, stream>>>(
      ys, (const float*)d_in[6], (const float*)d_in[7], Hm, mats, hy_b, mconst, xs0);

  WP wp;
  wp.W1[0] = (const float*)d_in[8];  wp.b1[0] = (const float*)d_in[9];
  wp.W2[0] = (const float*)d_in[10]; wp.b2[0] = (const float*)d_in[11];
  wp.W1[1] = (const float*)d_in[12]; wp.b1[1] = (const float*)d_in[13];
  wp.W2[1] = (const float*)d_in[14]; wp.b2[1] = (const float*)d_in[15];
  wp.W1[2] = (const float*)d_in[16]; wp.b1[2] = (const float*)d_in[17];
  wp.W2[2] = (const float*)d_in[18]; wp.b2[2] = (const float*)d_in[19];
  wp.Wih = (const float*)d_in[20]; wp.bih = (const float*)d_in[21];
  wp.Whh = (const float*)d_in[22]; wp.bhh = (const float*)d_in[23];
  wp.Wdec = (const float*)d_in[24]; wp.bdec = (const float*)d_in[25];
  wp.W1b = W1b; wp.W2b = W2b; wp.Wihb = Wihb; wp.Whhb = Whhb; wp.Wdecb = Wdecb;
  convert_weights_kernel<<<16, 256, 0, stream>>>(wp);

  FP P;
  P.Mmsg = Mmsg; P.mconst = mconst; P.hy_b = hy_b;
  P.W1b = W1b; P.W2b = W2b; P.Wihb = Wihb; P.Whhb = Whhb; P.Wdecb = Wdecb;
  P.out = out;

  for (int L = 0; L < NLNCH; L++) {
    int k0 = L * FUSE;
    P.k0 = k0;
    P.xs_src = (L == 0) ? xs0 : out + BXT + (size_t)(k0 - 1) * BXT;
    P.hx_src = (L == 0) ? hx0 : ((L & 1) ? hxA : hxB);
    P.hx_dst = (L & 1) ? hxB : hxA;
    fused_kernel<<<dim3(BB * NTI), dim3(512), 0, stream>>>(P);
  }
}